// Round 4
// baseline (195.047 us; speedup 1.0000x reference)
//
#include <hip/hip_runtime.h>
#include <hip/hip_bf16.h>
#include <math.h>

#define BB 1024
#define DD 64
#define HH 128

typedef _Float16 half8 __attribute__((ext_vector_type(8)));
typedef __fp16 fp16x2 __attribute__((ext_vector_type(2)));
typedef float floatx4 __attribute__((ext_vector_type(4)));

union H8 { fp16x2 p[4]; half8 v; };

// async global -> LDS, 16B per lane. lds base must be wave-uniform; HW adds lane*16.
__device__ __forceinline__ void async_cp16(const float* g, float* lds_wave_base) {
    __builtin_amdgcn_global_load_lds(
        (const __attribute__((address_space(1))) unsigned int*)g,
        (__attribute__((address_space(3))) unsigned int*)lds_wave_base,
        16, 0, 0);
}

// ---------------------------------------------------------------------------
// Prep (split over blockIdx.y for 2x parallelism, 256 blocks total):
//  y==0: c1[i,h] = x_i @ (Wi+Wd) + b1  (f32)          [reads Wi, Wd panels]
//  y==1: c2P = x_j @ (Wj-Wd) in hh-split MFMA C-fragment order [reads Wj, Wd]
//         c2P[(j>>4)*2048 + (h>>6)*1024 + ((h>>4)&3)*256
//             + ((j&15)>>2)*64 + (h&15)*4 + (j&3)]
//        + wpack (f16) = Wab in per-lane MFMA B-fragment order (blocks 0..31):
//         wpack[((hh*8 + t4*2 + s)*64 + l)*8 + jj]
//           = f16( Wab[s*32 + (l>>4)*8 + jj][hh*64 + t4*16 + (l&15)] )
// Grid (128,2) x 256. Block = 8 i rows x 32 h-quads; W1 reads are float4.
// ---------------------------------------------------------------------------
__global__ __launch_bounds__(256) void prep_kernel(
    const float* __restrict__ x, const float* __restrict__ W1,
    const float* __restrict__ b1,
    float* __restrict__ c1, float* __restrict__ c2P,
    _Float16* __restrict__ wpack)
{
    __shared__ float xs[8][DD];
    const int t = threadIdx.x;
    const int i0 = blockIdx.x * 8;
    xs[t >> 6][t & 63] = x[i0 * DD + t];
    xs[4 + (t >> 6)][t & 63] = x[i0 * DD + 256 + t];
    __syncthreads();

    const int ii = t >> 5;           // 0..7
    const int h4 = t & 31;           // h-quad
    const int h = h4 * 4;
    const int i = i0 + ii;

    if (blockIdx.y == 0) {
        float4 a1 = {0.f, 0.f, 0.f, 0.f};
        #pragma unroll 4
        for (int k = 0; k < DD; k++) {
            float4 wi = *(const float4*)(W1 + k * HH + h);
            float4 wd = *(const float4*)(W1 + (2 * DD + k) * HH + h);
            float xv = xs[ii][k];
            a1.x = fmaf(xv, wi.x + wd.x, a1.x);
            a1.y = fmaf(xv, wi.y + wd.y, a1.y);
            a1.z = fmaf(xv, wi.z + wd.z, a1.z);
            a1.w = fmaf(xv, wi.w + wd.w, a1.w);
        }
        float4 b1v = *(const float4*)(b1 + h);
        float4 c1v = {a1.x + b1v.x, a1.y + b1v.y, a1.z + b1v.z, a1.w + b1v.w};
        *(float4*)(c1 + i * HH + h) = c1v;
    } else {
        float4 a2 = {0.f, 0.f, 0.f, 0.f};
        #pragma unroll 4
        for (int k = 0; k < DD; k++) {
            float4 wj = *(const float4*)(W1 + (DD + k) * HH + h);
            float4 wd = *(const float4*)(W1 + (2 * DD + k) * HH + h);
            float xv = xs[ii][k];
            a2.x = fmaf(xv, wj.x - wd.x, a2.x);
            a2.y = fmaf(xv, wj.y - wd.y, a2.y);
            a2.z = fmaf(xv, wj.z - wd.z, a2.z);
            a2.w = fmaf(xv, wj.w - wd.w, a2.w);
        }
        // scatter a2 into hh-split fragment order
        const int jl = i & 15;
        float* cb = c2P + (i >> 4) * 2048 + (h >> 6) * 1024 + ((h >> 4) & 3) * 256 + (jl & 3);
        const int p0 = (jl >> 2) * 16 + (h & 15);
        cb[(p0 + 0) * 4] = a2.x;
        cb[(p0 + 1) * 4] = a2.y;
        cb[(p0 + 2) * 4] = a2.z;
        cb[(p0 + 3) * 4] = a2.w;

        if (blockIdx.x < 32) {
            int f = blockIdx.x * 256 + t;        // 0..8191
            int jj = f & 7;
            int l  = (f >> 3) & 63;
            int u  = f >> 9;                     // hh*8 + t4*2 + s
            int s  = u & 1, t4 = (u >> 1) & 3, hh = u >> 3;
            int k  = s * 32 + ((l >> 4) << 3) + jj;
            int hcol = hh * 64 + t4 * 16 + (l & 15);
            wpack[f] = (_Float16)W1[(3 * DD + k) * HH + hcol];
        }
    }
}

// ---------------------------------------------------------------------------
// Pair kernel v4 (full-h waves): Sp[jq][i][h] = sum_{j in quarter jq}
//   relu(|x_i-x_j| @ Wab + c1[i] + c2[j])   for ALL 128 h per wave.
// Rationale: the A-operand |x_i-x_j| is h-independent; the old hh-split
// built it twice per (i,j-tile) and read the xs tile twice from LDS.
// One wave now owns 1 i x 128 h: A-build VALU and xs LDS reads halve;
// wf doubles to 16 frags (64 VGPR), acc processed 4-at-a-time per hh half
// to cap live registers. launch_bounds(256,4) caps VGPR at 128.
// Grid 1024 = 256 ig x 4 jq. Block = 4 waves = 4 i. LDS 24 KB/block
// (xs 2x4KB + c2 full-tile 2x8KB), async double-buffered, shared by 4 waves.
// Per-element arithmetic order identical to v0 -> bitwise-same output.
// ---------------------------------------------------------------------------
__global__ __launch_bounds__(256, 4) void pair_kernel(
    const float* __restrict__ x, const float* __restrict__ c1,
    const float* __restrict__ c2P, const _Float16* __restrict__ wpack,
    float* __restrict__ Sp)
{
    __shared__ __align__(16) float xs[2][1024];   // 2 x 4 KB (16 j x 64 k, swizzled)
    __shared__ __align__(16) float c2s[2][2048];  // 2 x 8 KB (full-tile fragment order)

    const int t = threadIdx.x;
    const int wave = t >> 6;
    const int l = t & 63;
    const int quad = l >> 4, lm = l & 15;
    const int bid = blockIdx.x;
    const int ig = bid >> 2;         // 0..255
    const int jq = bid & 3;          // j quarter (fastest -> same-XCD blocks share jq)
    const int i = ig * 4 + wave;
    const int j0base = jq * 256;
    const int sw = lm & 7;

    // stage tile 0 (async): xs swizzled (4 KB); c2 full tile (8 KB, 2 chunks)
    async_cp16(x + (j0base + (t >> 4)) * DD + (((t & 15) ^ ((t >> 4) & 7)) << 2),
               &xs[0][0] + wave * 256);
    async_cp16(c2P + (j0base >> 4) * 2048 + t * 4,
               &c2s[0][0] + wave * 256);
    async_cp16(c2P + (j0base >> 4) * 2048 + (t + 256) * 4,
               &c2s[0][0] + 1024 + wave * 256);

    // wave-private register data (overlaps staging)
    float xi[16];
    {
        const float* xg = x + i * DD + quad * 8;
        *(float4*)(xi)      = *(const float4*)(xg);
        *(float4*)(xi + 4)  = *(const float4*)(xg + 4);
        *(float4*)(xi + 8)  = *(const float4*)(xg + 32);
        *(float4*)(xi + 12) = *(const float4*)(xg + 36);
    }
    float c1r[8];
    #pragma unroll
    for (int u = 0; u < 8; u++)      // u = hh2*4 + t4
        c1r[u] = c1[i * HH + (u >> 2) * 64 + (u & 3) * 16 + lm];
    half8 wf[16];
    #pragma unroll
    for (int u = 0; u < 16; u++)
        wf[u] = *(const half8*)(wpack + (u * 64 + l) * 8);

    float S[8] = {0.f, 0.f, 0.f, 0.f, 0.f, 0.f, 0.f, 0.f};

    for (int tile = 0; tile < 16; ++tile) {
        const int cur = tile & 1;
        __syncthreads();   // staged data for 'tile' landed; other buffer free

        if (tile < 15) {   // prefetch next tile (async)
            const int jn = j0base + (tile + 1) * 16;
            async_cp16(x + (jn + (t >> 4)) * DD + (((t & 15) ^ ((t >> 4) & 7)) << 2),
                       &xs[cur ^ 1][0] + wave * 256);
            async_cp16(c2P + (jn >> 4) * 2048 + t * 4,
                       &c2s[cur ^ 1][0] + wave * 256);
            async_cp16(c2P + (jn >> 4) * 2048 + (t + 256) * 4,
                       &c2s[cur ^ 1][0] + 1024 + wave * 256);
        }

        // A fragment (h-independent, built ONCE): row r=lm, chunks
        // quad*2, +1, +8, +9, swizzled by sw=lm&7
        const float* xb = &xs[cur][lm * 64];
        float4 a0 = *(const float4*)(xb + (((quad * 2)     ^ sw) << 2));
        float4 a1 = *(const float4*)(xb + (((quad * 2 + 1) ^ sw) << 2));
        float4 a2 = *(const float4*)(xb + (((quad * 2 + 8) ^ sw) << 2));
        float4 a3 = *(const float4*)(xb + (((quad * 2 + 9) ^ sw) << 2));
        H8 af0, af1;
        af0.p[0] = __builtin_amdgcn_cvt_pkrtz(fabsf(xi[0] - a0.x),  fabsf(xi[1] - a0.y));
        af0.p[1] = __builtin_amdgcn_cvt_pkrtz(fabsf(xi[2] - a0.z),  fabsf(xi[3] - a0.w));
        af0.p[2] = __builtin_amdgcn_cvt_pkrtz(fabsf(xi[4] - a1.x),  fabsf(xi[5] - a1.y));
        af0.p[3] = __builtin_amdgcn_cvt_pkrtz(fabsf(xi[6] - a1.z),  fabsf(xi[7] - a1.w));
        af1.p[0] = __builtin_amdgcn_cvt_pkrtz(fabsf(xi[8] - a2.x),  fabsf(xi[9] - a2.y));
        af1.p[1] = __builtin_amdgcn_cvt_pkrtz(fabsf(xi[10] - a2.z), fabsf(xi[11] - a2.w));
        af1.p[2] = __builtin_amdgcn_cvt_pkrtz(fabsf(xi[12] - a3.x), fabsf(xi[13] - a3.y));
        af1.p[3] = __builtin_amdgcn_cvt_pkrtz(fabsf(xi[14] - a3.z), fabsf(xi[15] - a3.w));

        // both h-halves consume the same af0/af1; acc lives 4 frags at a time
        #pragma unroll
        for (int hh2 = 0; hh2 < 2; hh2++) {
            floatx4 acc[4];
            #pragma unroll
            for (int t4 = 0; t4 < 4; t4++) {
                float4 c2v = *(const float4*)(&c2s[cur][hh2 * 1024 + t4 * 256 + l * 4]);
                acc[t4][0] = c2v.x + c1r[hh2 * 4 + t4];
                acc[t4][1] = c2v.y + c1r[hh2 * 4 + t4];
                acc[t4][2] = c2v.z + c1r[hh2 * 4 + t4];
                acc[t4][3] = c2v.w + c1r[hh2 * 4 + t4];
            }
            #pragma unroll
            for (int t4 = 0; t4 < 4; t4++) {
                acc[t4] = __builtin_amdgcn_mfma_f32_16x16x32_f16(af0.v, wf[hh2 * 8 + t4 * 2 + 0], acc[t4], 0, 0, 0);
                acc[t4] = __builtin_amdgcn_mfma_f32_16x16x32_f16(af1.v, wf[hh2 * 8 + t4 * 2 + 1], acc[t4], 0, 0, 0);
            }
            #pragma unroll
            for (int t4 = 0; t4 < 4; t4++) {
                S[hh2 * 4 + t4] += fmaxf(acc[t4][0], 0.f);
                S[hh2 * 4 + t4] += fmaxf(acc[t4][1], 0.f);
                S[hh2 * 4 + t4] += fmaxf(acc[t4][2], 0.f);
                S[hh2 * 4 + t4] += fmaxf(acc[t4][3], 0.f);
            }
        }
    }

    // reduce across the 4 quads (same h = lm+16*t4+64*hh2, different j-rows)
    #pragma unroll
    for (int u = 0; u < 8; u++) {
        S[u] += __shfl_xor(S[u], 16, 64);
        S[u] += __shfl_xor(S[u], 32, 64);
    }
    if (quad == 0) {
        #pragma unroll
        for (int u = 0; u < 8; u++)
            Sp[(jq * BB + i) * HH + (u >> 2) * 64 + (u & 3) * 16 + lm] = S[u];
    }
}

// ---------------------------------------------------------------------------
// Finish: per row i:  m = (b2 + (mean_j S) @ W2)/tau ; h = relu(m@Wa+ba);
//   y = h + x@Wr + br; out = LayerNorm(y)*gamma+beta.
// Grid 512 x 128. Block = 2 i rows x 64 lanes; each lane owns 2 h columns.
// ---------------------------------------------------------------------------
__global__ __launch_bounds__(128) void finish_kernel(
    const float* __restrict__ Sp, const float* __restrict__ W2,
    const float* __restrict__ b2, const float* __restrict__ x,
    const float* __restrict__ Wt, const float* __restrict__ bt,
    const float* __restrict__ Wa, const float* __restrict__ ba,
    const float* __restrict__ Wr, const float* __restrict__ br,
    const float* __restrict__ gamma, const float* __restrict__ beta,
    float* __restrict__ out)
{
    __shared__ float Srow[2][HH];
    __shared__ float mrow[2][HH];
    __shared__ float xrowS[2][DD];
    __shared__ float taus[2];
    const int t = threadIdx.x;      // 0..127
    const int ii = t >> 6;          // 0..1
    const int l = t & 63;
    const int i0 = blockIdx.x * 2;
    const int i = i0 + ii;
    const int h = l * 2;

    {
        float2 s = {0.f, 0.f};
        #pragma unroll
        for (int q = 0; q < 4; q++) {
            float2 v = *(const float2*)(Sp + (q * BB + i) * HH + h);
            s.x += v.x; s.y += v.y;
        }
        const float inv = 1.0f / (float)BB;
        Srow[ii][h]     = s.x * inv;
        Srow[ii][h + 1] = s.y * inv;
    }
    float xv0 = x[i * DD + l];
    xrowS[ii][l] = xv0;

    {
        float p = xv0 * Wt[l];
        #pragma unroll
        for (int off = 32; off; off >>= 1) p += __shfl_xor(p, off, 64);
        if (l == 0) {
            float z = p + bt[0];
            float sp = (z > 20.f) ? z : log1pf(expf(z));
            taus[ii] = fmaxf(sp, 0.01f) + 1.0f;
        }
    }
    __syncthreads();

    float2 acc = *(const float2*)(b2 + h);
    #pragma unroll 8
    for (int k = 0; k < HH; k++) {
        float2 w = *(const float2*)(W2 + k * HH + h);
        float sv = Srow[ii][k];
        acc.x = fmaf(sv, w.x, acc.x); acc.y = fmaf(sv, w.y, acc.y);
    }
    const float itau = 1.0f / taus[ii];
    mrow[ii][h]     = acc.x * itau;
    mrow[ii][h + 1] = acc.y * itau;
    __syncthreads();

    float2 a2 = *(const float2*)(ba + h);
    #pragma unroll 8
    for (int k = 0; k < HH; k++) {
        float2 w = *(const float2*)(Wa + k * HH + h);
        float sv = mrow[ii][k];
        a2.x = fmaf(sv, w.x, a2.x); a2.y = fmaf(sv, w.y, a2.y);
    }
    float2 brv = *(const float2*)(br + h);
    float2 y = {fmaxf(a2.x, 0.f) + brv.x, fmaxf(a2.y, 0.f) + brv.y};
    #pragma unroll 8
    for (int d = 0; d < DD; d++) {
        float2 w = *(const float2*)(Wr + d * HH + h);
        float xv = xrowS[ii][d];
        y.x = fmaf(xv, w.x, y.x); y.y = fmaf(xv, w.y, y.y);
    }

    float p = y.x + y.y;
    #pragma unroll
    for (int off = 32; off; off >>= 1) p += __shfl_xor(p, off, 64);
    float mu = p * (1.0f / (float)HH);
    float2 dy = {y.x - mu, y.y - mu};
    float q = dy.x * dy.x + dy.y * dy.y;
    #pragma unroll
    for (int off = 32; off; off >>= 1) q += __shfl_xor(q, off, 64);
    float rs = rsqrtf(q * (1.0f / (float)HH) + 1e-5f);
    float2 gv = *(const float2*)(gamma + h);
    float2 bv = *(const float2*)(beta + h);
    float2 o = {dy.x * rs * gv.x + bv.x, dy.y * rs * gv.y + bv.y};
    *(float2*)(out + i * HH + h) = o;
}

// ---------------------------------------------------------------------------
extern "C" void kernel_launch(void* const* d_in, const int* in_sizes, int n_in,
                              void* d_out, int out_size, void* d_ws, size_t ws_size,
                              hipStream_t stream)
{
    const float* x     = (const float*)d_in[0];
    const float* W1    = (const float*)d_in[1];
    const float* b1    = (const float*)d_in[2];
    const float* W2    = (const float*)d_in[3];
    const float* b2    = (const float*)d_in[4];
    const float* Wt    = (const float*)d_in[5];
    const float* bt    = (const float*)d_in[6];
    const float* Wa    = (const float*)d_in[7];
    const float* ba    = (const float*)d_in[8];
    const float* Wr    = (const float*)d_in[9];
    const float* br    = (const float*)d_in[10];
    const float* gamma = (const float*)d_in[11];
    const float* beta  = (const float*)d_in[12];
    float* out = (float*)d_out;

    char* ws = (char*)d_ws;
    float*     c1    = (float*)(ws);                         // 512 KB
    float*     c2P   = (float*)(ws + (512 << 10));           // 512 KB
    _Float16*  wpack = (_Float16*)(ws + (1024 << 10));       // 16 KB
    float*     Sp    = (float*)(ws + (1056 << 10));          // 2 MB

    prep_kernel<<<dim3(128, 2), 256, 0, stream>>>(x, W1, b1, c1, c2P, wpack);
    pair_kernel<<<1024, 256, 0, stream>>>(x, c1, c2P, wpack, Sp);
    finish_kernel<<<512, 128, 0, stream>>>(Sp, W2, b2, x, Wt, bt,
                                           Wa, ba, Wr, br, gamma, beta, out);
}

// Round 5
// 127.873 us; speedup vs baseline: 1.5253x; 1.5253x over previous
//
#include <hip/hip_runtime.h>
#include <hip/hip_bf16.h>
#include <math.h>

#define BB 1024
#define DD 64
#define HH 128

typedef _Float16 half8 __attribute__((ext_vector_type(8)));
typedef __fp16 fp16x2 __attribute__((ext_vector_type(2)));
typedef float floatx4 __attribute__((ext_vector_type(4)));

union H8 { fp16x2 p[4]; half8 v; };

// async global -> LDS, 16B per lane. lds base must be wave-uniform; HW adds lane*16.
__device__ __forceinline__ void async_cp16(const float* g, float* lds_wave_base) {
    __builtin_amdgcn_global_load_lds(
        (const __attribute__((address_space(1))) unsigned int*)g,
        (__attribute__((address_space(3))) unsigned int*)lds_wave_base,
        16, 0, 0);
}

// ---------------------------------------------------------------------------
// Prep v3 (latency-hiding rewrite: 4 waves/SIMD, same arithmetic):
//  grid (512, 2) x 256. Block = 2 i rows x 128 h columns (1 h per lane).
//  y==0: c1[i,h] = x_i @ (Wi+Wd) + b1
//  y==1: c2P scatter of x_j @ (Wj-Wd), + wpack (blocks 0..31)
//  Per-output k-chain order identical to previous versions (bitwise-same).
//  c2P[(j>>4)*2048 + (h>>6)*1024 + ((h>>4)&3)*256
//      + ((j&15)>>2)*64 + (h&15)*4 + (j&3)]
//  wpack[((hh*8 + t4*2 + s)*64 + l)*8 + jj]
//      = f16( Wab[s*32 + (l>>4)*8 + jj][hh*64 + t4*16 + (l&15)] )
// ---------------------------------------------------------------------------
__global__ __launch_bounds__(256) void prep_kernel(
    const float* __restrict__ x, const float* __restrict__ W1,
    const float* __restrict__ b1,
    float* __restrict__ c1, float* __restrict__ c2P,
    _Float16* __restrict__ wpack)
{
    __shared__ float xs[2][DD];
    const int t = threadIdx.x;        // 0..255
    const int i0 = blockIdx.x * 2;
    if (t < 128) xs[t >> 6][t & 63] = x[i0 * DD + t];
    __syncthreads();

    const int ii = t >> 7;            // 0..1
    const int h = t & 127;            // h column (coalesced across lanes)
    const int i = i0 + ii;

    if (blockIdx.y == 0) {
        float a1 = 0.f;
        #pragma unroll 8
        for (int k = 0; k < DD; k++) {
            float wi = W1[k * HH + h];
            float wd = W1[(2 * DD + k) * HH + h];
            a1 = fmaf(xs[ii][k], wi + wd, a1);
        }
        c1[i * HH + h] = a1 + b1[h];
    } else {
        float a2 = 0.f;
        #pragma unroll 8
        for (int k = 0; k < DD; k++) {
            float wj = W1[(DD + k) * HH + h];
            float wd = W1[(2 * DD + k) * HH + h];
            a2 = fmaf(xs[ii][k], wj - wd, a2);
        }
        // scatter into hh-split MFMA C-fragment order (single column h)
        c2P[(i >> 4) * 2048 + (h >> 6) * 1024 + ((h >> 4) & 3) * 256
            + ((i & 15) >> 2) * 64 + (h & 15) * 4 + (i & 3)] = a2;

        if (blockIdx.x < 32) {
            int f = blockIdx.x * 256 + t;        // 0..8191
            int jj = f & 7;
            int l  = (f >> 3) & 63;
            int u  = f >> 9;                     // hh*8 + t4*2 + s
            int s  = u & 1, t4 = (u >> 1) & 3, hh = u >> 3;
            int k  = s * 32 + ((l >> 4) << 3) + jj;
            int hcol = hh * 64 + t4 * 16 + (l & 15);
            wpack[f] = (_Float16)W1[(3 * DD + k) * HH + hcol];
        }
    }
}

// ---------------------------------------------------------------------------
// Pair kernel (R0/R3 structure, empirically best — UNCHANGED):
//   Sp[jq][i][hh*64+..] = sum_{j in quarter jq}
//     relu(|x_i-x_j| @ Wab[:,h-half] + c1[i] + c2[j])
// Grid 2048 = 256 ig x 2 hh x 4 jq. Block = 4 waves = 4 i, one h-half.
// Per-wave: 1 i, 64 h (wf = 8 f16 frags = 32 VGPR, acc 16 -> VGPR-resident).
// xs (f32, XOR-swizzled) + c2 half-tile (4 KB) staged async, double-buffered,
// SHARED by the 4 waves. A-operand built via v_cvt_pkrtz (abs folded).
// ---------------------------------------------------------------------------
__global__ __launch_bounds__(256, 4) void pair_kernel(
    const float* __restrict__ x, const float* __restrict__ c1,
    const float* __restrict__ c2P, const _Float16* __restrict__ wpack,
    float* __restrict__ Sp)
{
    __shared__ __align__(16) float xs[2][1024];   // 2 x 4 KB (16 j x 64 k, swizzled)
    __shared__ __align__(16) float c2s[2][1024];  // 2 x 4 KB (hh-half fragment order)

    const int t = threadIdx.x;
    const int wave = t >> 6;
    const int l = t & 63;
    const int quad = l >> 4, lm = l & 15;
    const int bid = blockIdx.x;
    const int ig = bid >> 3;
    const int hh = (bid >> 2) & 1;
    const int jq = bid & 3;
    const int i = ig * 4 + wave;
    const int j0base = jq * 256;
    const int sw = lm & 7;

    // stage tile 0 (async): xs swizzled; c2 half-tile
    async_cp16(x + (j0base + (t >> 4)) * DD + (((t & 15) ^ ((t >> 4) & 7)) << 2),
               &xs[0][0] + wave * 256);
    async_cp16(c2P + (j0base >> 4) * 2048 + hh * 1024 + t * 4,
               &c2s[0][0] + wave * 256);

    // wave-private register data (overlaps staging)
    float xi[16];
    {
        const float* xg = x + i * DD + quad * 8;
        *(float4*)(xi)      = *(const float4*)(xg);
        *(float4*)(xi + 4)  = *(const float4*)(xg + 4);
        *(float4*)(xi + 8)  = *(const float4*)(xg + 32);
        *(float4*)(xi + 12) = *(const float4*)(xg + 36);
    }
    float c1r[4];
    #pragma unroll
    for (int t4 = 0; t4 < 4; t4++)
        c1r[t4] = c1[i * HH + hh * 64 + t4 * 16 + lm];
    half8 wf[8];
    #pragma unroll
    for (int u = 0; u < 8; u++)
        wf[u] = *(const half8*)(wpack + ((hh * 8 + u) * 64 + l) * 8);

    float S[4] = {0.f, 0.f, 0.f, 0.f};

    for (int tile = 0; tile < 16; ++tile) {
        const int cur = tile & 1;
        __syncthreads();   // staged data for 'tile' landed; other buffer free

        if (tile < 15) {   // prefetch next tile (async)
            const int jn = j0base + (tile + 1) * 16;
            async_cp16(x + (jn + (t >> 4)) * DD + (((t & 15) ^ ((t >> 4) & 7)) << 2),
                       &xs[cur ^ 1][0] + wave * 256);
            async_cp16(c2P + (jn >> 4) * 2048 + hh * 1024 + t * 4,
                       &c2s[cur ^ 1][0] + wave * 256);
        }

        // acc init = c2 (fragment-ordered LDS b128) + c1
        floatx4 acc[4];
        #pragma unroll
        for (int t4 = 0; t4 < 4; t4++) {
            float4 c2v = *(const float4*)(&c2s[cur][t4 * 256 + l * 4]);
            acc[t4][0] = c2v.x + c1r[t4];
            acc[t4][1] = c2v.y + c1r[t4];
            acc[t4][2] = c2v.z + c1r[t4];
            acc[t4][3] = c2v.w + c1r[t4];
        }

        // A fragment: row r=lm, chunks quad*2, +1, +8, +9, swizzled by sw=lm&7
        const float* xb = &xs[cur][lm * 64];
        float4 a0 = *(const float4*)(xb + (((quad * 2)     ^ sw) << 2));
        float4 a1 = *(const float4*)(xb + (((quad * 2 + 1) ^ sw) << 2));
        float4 a2 = *(const float4*)(xb + (((quad * 2 + 8) ^ sw) << 2));
        float4 a3 = *(const float4*)(xb + (((quad * 2 + 9) ^ sw) << 2));
        H8 af0, af1;
        af0.p[0] = __builtin_amdgcn_cvt_pkrtz(fabsf(xi[0] - a0.x),  fabsf(xi[1] - a0.y));
        af0.p[1] = __builtin_amdgcn_cvt_pkrtz(fabsf(xi[2] - a0.z),  fabsf(xi[3] - a0.w));
        af0.p[2] = __builtin_amdgcn_cvt_pkrtz(fabsf(xi[4] - a1.x),  fabsf(xi[5] - a1.y));
        af0.p[3] = __builtin_amdgcn_cvt_pkrtz(fabsf(xi[6] - a1.z),  fabsf(xi[7] - a1.w));
        af1.p[0] = __builtin_amdgcn_cvt_pkrtz(fabsf(xi[8] - a2.x),  fabsf(xi[9] - a2.y));
        af1.p[1] = __builtin_amdgcn_cvt_pkrtz(fabsf(xi[10] - a2.z), fabsf(xi[11] - a2.w));
        af1.p[2] = __builtin_amdgcn_cvt_pkrtz(fabsf(xi[12] - a3.x), fabsf(xi[13] - a3.y));
        af1.p[3] = __builtin_amdgcn_cvt_pkrtz(fabsf(xi[14] - a3.z), fabsf(xi[15] - a3.w));

        #pragma unroll
        for (int t4 = 0; t4 < 4; t4++) {
            acc[t4] = __builtin_amdgcn_mfma_f32_16x16x32_f16(af0.v, wf[t4 * 2 + 0], acc[t4], 0, 0, 0);
            acc[t4] = __builtin_amdgcn_mfma_f32_16x16x32_f16(af1.v, wf[t4 * 2 + 1], acc[t4], 0, 0, 0);
        }
        #pragma unroll
        for (int t4 = 0; t4 < 4; t4++) {
            S[t4] += fmaxf(acc[t4][0], 0.f);
            S[t4] += fmaxf(acc[t4][1], 0.f);
            S[t4] += fmaxf(acc[t4][2], 0.f);
            S[t4] += fmaxf(acc[t4][3], 0.f);
        }
    }

    // reduce across the 4 quads (same h = lm+16*t4, different j-rows)
    #pragma unroll
    for (int t4 = 0; t4 < 4; t4++) {
        S[t4] += __shfl_xor(S[t4], 16, 64);
        S[t4] += __shfl_xor(S[t4], 32, 64);
    }
    if (quad == 0) {
        #pragma unroll
        for (int t4 = 0; t4 < 4; t4++)
            Sp[(jq * BB + i) * HH + hh * 64 + t4 * 16 + lm] = S[t4];
    }
}

// ---------------------------------------------------------------------------
// Finish v3 (latency-hiding rewrite: 2 waves/SIMD): per row i:
//   m = (b2 + (mean_j S) @ W2)/tau ; h = relu(m@Wa+ba);
//   y = h + x@Wr + br; out = LayerNorm(y)*gamma+beta.
// Grid 1024 x 128. Block = 1 i row, lane = 1 h column (coalesced weight
// reads). LN reductions: 64-wide shfl tree + 2-way LDS combine across the
// block's two waves.
// ---------------------------------------------------------------------------
__global__ __launch_bounds__(128) void finish_kernel(
    const float* __restrict__ Sp, const float* __restrict__ W2,
    const float* __restrict__ b2, const float* __restrict__ x,
    const float* __restrict__ Wt, const float* __restrict__ bt,
    const float* __restrict__ Wa, const float* __restrict__ ba,
    const float* __restrict__ Wr, const float* __restrict__ br,
    const float* __restrict__ gamma, const float* __restrict__ beta,
    float* __restrict__ out)
{
    __shared__ float Srow[HH];
    __shared__ float mrow[HH];
    __shared__ float xrow[DD];
    __shared__ float red[2][2];
    __shared__ float tau_s;
    const int t = threadIdx.x;      // 0..127 = h column
    const int h = t;
    const int wv = t >> 6;          // 0..1
    const int l = t & 63;
    const int i = blockIdx.x;

    {
        float s = 0.f;
        #pragma unroll
        for (int q = 0; q < 4; q++)
            s += Sp[(q * BB + i) * HH + h];
        Srow[h] = s * (1.0f / (float)BB);
    }
    if (wv == 0) {
        float xv = x[i * DD + l];
        xrow[l] = xv;
        float p = xv * Wt[l];
        #pragma unroll
        for (int off = 32; off; off >>= 1) p += __shfl_xor(p, off, 64);
        if (l == 0) {
            float z = p + bt[0];
            float sp = (z > 20.f) ? z : log1pf(expf(z));
            tau_s = fmaxf(sp, 0.01f) + 1.0f;
        }
    }
    __syncthreads();

    float acc = b2[h];
    #pragma unroll 8
    for (int k = 0; k < HH; k++)
        acc = fmaf(Srow[k], W2[k * HH + h], acc);
    const float itau = 1.0f / tau_s;
    mrow[h] = acc * itau;
    __syncthreads();

    float a2 = ba[h];
    #pragma unroll 8
    for (int k = 0; k < HH; k++)
        a2 = fmaf(mrow[k], Wa[k * HH + h], a2);
    float y = fmaxf(a2, 0.f) + br[h];
    #pragma unroll 8
    for (int d = 0; d < DD; d++)
        y = fmaf(xrow[d], Wr[d * HH + h], y);

    // LayerNorm over 128 h (2 waves): shfl tree + LDS combine
    float p = y;
    #pragma unroll
    for (int off = 32; off; off >>= 1) p += __shfl_xor(p, off, 64);
    if (l == 0) red[0][wv] = p;
    __syncthreads();
    float mu = (red[0][0] + red[0][1]) * (1.0f / (float)HH);
    float dy = y - mu;
    float q = dy * dy;
    #pragma unroll
    for (int off = 32; off; off >>= 1) q += __shfl_xor(q, off, 64);
    if (l == 0) red[1][wv] = q;
    __syncthreads();
    float rs = rsqrtf((red[1][0] + red[1][1]) * (1.0f / (float)HH) + 1e-5f);
    out[i * HH + h] = dy * rs * gamma[h] + beta[h];
}

// ---------------------------------------------------------------------------
extern "C" void kernel_launch(void* const* d_in, const int* in_sizes, int n_in,
                              void* d_out, int out_size, void* d_ws, size_t ws_size,
                              hipStream_t stream)
{
    const float* x     = (const float*)d_in[0];
    const float* W1    = (const float*)d_in[1];
    const float* b1    = (const float*)d_in[2];
    const float* W2    = (const float*)d_in[3];
    const float* b2    = (const float*)d_in[4];
    const float* Wt    = (const float*)d_in[5];
    const float* bt    = (const float*)d_in[6];
    const float* Wa    = (const float*)d_in[7];
    const float* ba    = (const float*)d_in[8];
    const float* Wr    = (const float*)d_in[9];
    const float* br    = (const float*)d_in[10];
    const float* gamma = (const float*)d_in[11];
    const float* beta  = (const float*)d_in[12];
    float* out = (float*)d_out;

    char* ws = (char*)d_ws;
    float*     c1    = (float*)(ws);                         // 512 KB
    float*     c2P   = (float*)(ws + (512 << 10));           // 512 KB
    _Float16*  wpack = (_Float16*)(ws + (1024 << 10));       // 16 KB
    float*     Sp    = (float*)(ws + (1056 << 10));          // 2 MB

    prep_kernel<<<dim3(512, 2), 256, 0, stream>>>(x, W1, b1, c1, c2P, wpack);
    pair_kernel<<<2048, 256, 0, stream>>>(x, c1, c2P, wpack, Sp);
    finish_kernel<<<1024, 128, 0, stream>>>(Sp, W2, b2, x, Wt, bt,
                                            Wa, ba, Wr, br, gamma, beta, out);
}

// Round 7
// 126.590 us; speedup vs baseline: 1.5408x; 1.0101x over previous
//
#include <hip/hip_runtime.h>
#include <hip/hip_bf16.h>
#include <math.h>

#define BB 1024
#define DD 64
#define HH 128

typedef _Float16 half8 __attribute__((ext_vector_type(8)));
typedef __fp16 fp16x2 __attribute__((ext_vector_type(2)));
typedef float floatx4 __attribute__((ext_vector_type(4)));

union H8 { fp16x2 p[4]; half8 v; };

// async global -> LDS, 16B per lane. lds base must be wave-uniform; HW adds lane*16.
__device__ __forceinline__ void async_cp16(const float* g, float* lds_wave_base) {
    __builtin_amdgcn_global_load_lds(
        (const __attribute__((address_space(1))) unsigned int*)g,
        (__attribute__((address_space(3))) unsigned int*)lds_wave_base,
        16, 0, 0);
}

// ---------------------------------------------------------------------------
// Prep v3 (4 waves/SIMD, same arithmetic):
//  grid (512, 2) x 256. Block = 2 i rows x 128 h columns (1 h per lane).
//  y==0: c1[i,h] = x_i @ (Wi+Wd) + b1
//  y==1: c2P scatter of x_j @ (Wj-Wd), + wpack (blocks 0..31)
//  c2P[(j>>4)*2048 + (h>>6)*1024 + ((h>>4)&3)*256
//      + ((j&15)>>2)*64 + (h&15)*4 + (j&3)]
//  wpack[((hh*8 + t4*2 + s)*64 + l)*8 + jj]
//      = f16( Wab[s*32 + (l>>4)*8 + jj][hh*64 + t4*16 + (l&15)] )
// ---------------------------------------------------------------------------
__global__ __launch_bounds__(256) void prep_kernel(
    const float* __restrict__ x, const float* __restrict__ W1,
    const float* __restrict__ b1,
    float* __restrict__ c1, float* __restrict__ c2P,
    _Float16* __restrict__ wpack)
{
    __shared__ float xs[2][DD];
    const int t = threadIdx.x;        // 0..255
    const int i0 = blockIdx.x * 2;
    if (t < 128) xs[t >> 6][t & 63] = x[i0 * DD + t];
    __syncthreads();

    const int ii = t >> 7;            // 0..1
    const int h = t & 127;            // h column (coalesced across lanes)
    const int i = i0 + ii;

    if (blockIdx.y == 0) {
        float a1 = 0.f;
        #pragma unroll 8
        for (int k = 0; k < DD; k++) {
            float wi = W1[k * HH + h];
            float wd = W1[(2 * DD + k) * HH + h];
            a1 = fmaf(xs[ii][k], wi + wd, a1);
        }
        c1[i * HH + h] = a1 + b1[h];
    } else {
        float a2 = 0.f;
        #pragma unroll 8
        for (int k = 0; k < DD; k++) {
            float wj = W1[(DD + k) * HH + h];
            float wd = W1[(2 * DD + k) * HH + h];
            a2 = fmaf(xs[ii][k], wj - wd, a2);
        }
        // scatter into hh-split MFMA C-fragment order (single column h)
        c2P[(i >> 4) * 2048 + (h >> 6) * 1024 + ((h >> 4) & 3) * 256
            + ((i & 15) >> 2) * 64 + (h & 15) * 4 + (i & 3)] = a2;

        if (blockIdx.x < 32) {
            int f = blockIdx.x * 256 + t;        // 0..8191
            int jj = f & 7;
            int l  = (f >> 3) & 63;
            int u  = f >> 9;                     // hh*8 + t4*2 + s
            int s  = u & 1, t4 = (u >> 1) & 3, hh = u >> 3;
            int k  = s * 32 + ((l >> 4) << 3) + jj;
            int hcol = hh * 64 + t4 * 16 + (l & 15);
            wpack[f] = (_Float16)W1[(3 * DD + k) * HH + hcol];
        }
    }
}

// ---------------------------------------------------------------------------
// Pair kernel v5: Sp[jq][i][hh*64+..] = sum_{j in quarter jq}
//     relu(|x_i-x_j| @ Wab[:,h-half] + c1[i] + c2[j])
// Grid 1024 = 128 ig x 2 hh x 4 jq. Block = 4 waves x 2 i = 8 i rows.
// Changes vs v0/R3 (which ran 43.6us, VALU 47% / LDS ~47% / Mfma 15%):
//  (a) 2 i per wave: xs tile reads + staging amortized over 2 i
//      (per-i ds_read_b128: 8 -> 6; c2 re-read for iB to cap VGPR).
//  (b) max-fold: relu(mfma + c2 + c1) = max(mfma_with_C=c2, -c1) + c1.
//      c2 loads straight into the MFMA C operand (no acc-init adds);
//      -c1 is a free VOP input modifier; the +c1 term is hoisted to ONE
//      fmaf(64*c1) per S register after the tile loop (exact algebra,
//      ~1ulp reassociation).
//  (c) launch_bounds(256,3): VGPR cap ~170 for this ~135-reg kernel —
//      avoids R4's spill (watch FETCH_SIZE stays ~2.4MB).
// ---------------------------------------------------------------------------
__global__ __launch_bounds__(256, 3) void pair_kernel(
    const float* __restrict__ x, const float* __restrict__ c1,
    const float* __restrict__ c2P, const _Float16* __restrict__ wpack,
    float* __restrict__ Sp)
{
    __shared__ __align__(16) float xs[2][1024];   // 2 x 4 KB (16 j x 64 k, swizzled)
    __shared__ __align__(16) float c2s[2][1024];  // 2 x 4 KB (hh-half fragment order)

    const int t = threadIdx.x;
    const int wave = t >> 6;
    const int l = t & 63;
    const int quad = l >> 4, lm = l & 15;
    const int bid = blockIdx.x;
    const int ig = bid >> 3;         // 0..127 (8 i rows per block)
    const int hh = (bid >> 2) & 1;
    const int jq = bid & 3;
    const int iA = ig * 8 + wave * 2;
    const int iB = iA + 1;
    const int j0base = jq * 256;
    const int sw = lm & 7;

    // stage tile 0 (async): xs swizzled; c2 half-tile (identical to v0)
    async_cp16(x + (j0base + (t >> 4)) * DD + (((t & 15) ^ ((t >> 4) & 7)) << 2),
               &xs[0][0] + wave * 256);
    async_cp16(c2P + (j0base >> 4) * 2048 + hh * 1024 + t * 4,
               &c2s[0][0] + wave * 256);

    // wave-private register data (overlaps staging)
    float xiA[16], xiB[16];
    {
        const float* xg = x + iA * DD + quad * 8;
        *(float4*)(xiA)      = *(const float4*)(xg);
        *(float4*)(xiA + 4)  = *(const float4*)(xg + 4);
        *(float4*)(xiA + 8)  = *(const float4*)(xg + 32);
        *(float4*)(xiA + 12) = *(const float4*)(xg + 36);
        const float* xh = x + iB * DD + quad * 8;
        *(float4*)(xiB)      = *(const float4*)(xh);
        *(float4*)(xiB + 4)  = *(const float4*)(xh + 4);
        *(float4*)(xiB + 8)  = *(const float4*)(xh + 32);
        *(float4*)(xiB + 12) = *(const float4*)(xh + 36);
    }
    float c1A[4], c1B[4];
    #pragma unroll
    for (int t4 = 0; t4 < 4; t4++) {
        c1A[t4] = c1[iA * HH + hh * 64 + t4 * 16 + lm];
        c1B[t4] = c1[iB * HH + hh * 64 + t4 * 16 + lm];
    }
    half8 wf[8];
    #pragma unroll
    for (int u = 0; u < 8; u++)
        wf[u] = *(const half8*)(wpack + ((hh * 8 + u) * 64 + l) * 8);

    float SA[4] = {0.f, 0.f, 0.f, 0.f};
    float SB[4] = {0.f, 0.f, 0.f, 0.f};

    for (int tile = 0; tile < 16; ++tile) {
        const int cur = tile & 1;
        __syncthreads();   // staged data for 'tile' landed; other buffer free

        if (tile < 15) {   // prefetch next tile (async)
            const int jn = j0base + (tile + 1) * 16;
            async_cp16(x + (jn + (t >> 4)) * DD + (((t & 15) ^ ((t >> 4) & 7)) << 2),
                       &xs[cur ^ 1][0] + wave * 256);
            async_cp16(c2P + (jn >> 4) * 2048 + hh * 1024 + t * 4,
                       &c2s[cur ^ 1][0] + wave * 256);
        }

        // A data (h-independent): row r=lm, chunks quad*2,+1,+8,+9, sw-swizzled
        const float* xb = &xs[cur][lm * 64];
        float4 a0 = *(const float4*)(xb + (((quad * 2)     ^ sw) << 2));
        float4 a1 = *(const float4*)(xb + (((quad * 2 + 1) ^ sw) << 2));
        float4 a2 = *(const float4*)(xb + (((quad * 2 + 8) ^ sw) << 2));
        float4 a3 = *(const float4*)(xb + (((quad * 2 + 9) ^ sw) << 2));

        // build BOTH i's A-fragments while a0..a3 live (then freed)
        H8 afA0, afA1, afB0, afB1;
        afA0.p[0] = __builtin_amdgcn_cvt_pkrtz(fabsf(xiA[0] - a0.x),  fabsf(xiA[1] - a0.y));
        afA0.p[1] = __builtin_amdgcn_cvt_pkrtz(fabsf(xiA[2] - a0.z),  fabsf(xiA[3] - a0.w));
        afA0.p[2] = __builtin_amdgcn_cvt_pkrtz(fabsf(xiA[4] - a1.x),  fabsf(xiA[5] - a1.y));
        afA0.p[3] = __builtin_amdgcn_cvt_pkrtz(fabsf(xiA[6] - a1.z),  fabsf(xiA[7] - a1.w));
        afA1.p[0] = __builtin_amdgcn_cvt_pkrtz(fabsf(xiA[8] - a2.x),  fabsf(xiA[9] - a2.y));
        afA1.p[1] = __builtin_amdgcn_cvt_pkrtz(fabsf(xiA[10] - a2.z), fabsf(xiA[11] - a2.w));
        afA1.p[2] = __builtin_amdgcn_cvt_pkrtz(fabsf(xiA[12] - a3.x), fabsf(xiA[13] - a3.y));
        afA1.p[3] = __builtin_amdgcn_cvt_pkrtz(fabsf(xiA[14] - a3.z), fabsf(xiA[15] - a3.w));
        afB0.p[0] = __builtin_amdgcn_cvt_pkrtz(fabsf(xiB[0] - a0.x),  fabsf(xiB[1] - a0.y));
        afB0.p[1] = __builtin_amdgcn_cvt_pkrtz(fabsf(xiB[2] - a0.z),  fabsf(xiB[3] - a0.w));
        afB0.p[2] = __builtin_amdgcn_cvt_pkrtz(fabsf(xiB[4] - a1.x),  fabsf(xiB[5] - a1.y));
        afB0.p[3] = __builtin_amdgcn_cvt_pkrtz(fabsf(xiB[6] - a1.z),  fabsf(xiB[7] - a1.w));
        afB1.p[0] = __builtin_amdgcn_cvt_pkrtz(fabsf(xiB[8] - a2.x),  fabsf(xiB[9] - a2.y));
        afB1.p[1] = __builtin_amdgcn_cvt_pkrtz(fabsf(xiB[10] - a2.z), fabsf(xiB[11] - a2.w));
        afB1.p[2] = __builtin_amdgcn_cvt_pkrtz(fabsf(xiB[12] - a3.x), fabsf(xiB[13] - a3.y));
        afB1.p[3] = __builtin_amdgcn_cvt_pkrtz(fabsf(xiB[14] - a3.z), fabsf(xiB[15] - a3.w));

        // --- i = iA: c2 loads directly into MFMA C; relu via max(.., -c1) ---
        {
            floatx4 acc[4];
            #pragma unroll
            for (int t4 = 0; t4 < 4; t4++)
                acc[t4] = *(const floatx4*)(&c2s[cur][t4 * 256 + l * 4]);
            #pragma unroll
            for (int t4 = 0; t4 < 4; t4++) {
                acc[t4] = __builtin_amdgcn_mfma_f32_16x16x32_f16(afA0.v, wf[t4 * 2 + 0], acc[t4], 0, 0, 0);
                acc[t4] = __builtin_amdgcn_mfma_f32_16x16x32_f16(afA1.v, wf[t4 * 2 + 1], acc[t4], 0, 0, 0);
            }
            #pragma unroll
            for (int t4 = 0; t4 < 4; t4++) {
                SA[t4] += fmaxf(acc[t4][0], -c1A[t4]);
                SA[t4] += fmaxf(acc[t4][1], -c1A[t4]);
                SA[t4] += fmaxf(acc[t4][2], -c1A[t4]);
                SA[t4] += fmaxf(acc[t4][3], -c1A[t4]);
            }
        }
        // --- i = iB (c2 re-read from LDS; saves 16 live VGPRs) ---
        {
            floatx4 acc[4];
            #pragma unroll
            for (int t4 = 0; t4 < 4; t4++)
                acc[t4] = *(const floatx4*)(&c2s[cur][t4 * 256 + l * 4]);
            #pragma unroll
            for (int t4 = 0; t4 < 4; t4++) {
                acc[t4] = __builtin_amdgcn_mfma_f32_16x16x32_f16(afB0.v, wf[t4 * 2 + 0], acc[t4], 0, 0, 0);
                acc[t4] = __builtin_amdgcn_mfma_f32_16x16x32_f16(afB1.v, wf[t4 * 2 + 1], acc[t4], 0, 0, 0);
            }
            #pragma unroll
            for (int t4 = 0; t4 < 4; t4++) {
                SB[t4] += fmaxf(acc[t4][0], -c1B[t4]);
                SB[t4] += fmaxf(acc[t4][1], -c1B[t4]);
                SB[t4] += fmaxf(acc[t4][2], -c1B[t4]);
                SB[t4] += fmaxf(acc[t4][3], -c1B[t4]);
            }
        }
    }

    // hoisted +c1 term: each S reg accumulated 64 j-rows (16 tiles x 4 regs)
    #pragma unroll
    for (int t4 = 0; t4 < 4; t4++) {
        SA[t4] = fmaf(64.f, c1A[t4], SA[t4]);
        SB[t4] = fmaf(64.f, c1B[t4], SB[t4]);
    }
    // reduce across the 4 quads (same h = lm+16*t4, different j-rows)
    #pragma unroll
    for (int t4 = 0; t4 < 4; t4++) {
        SA[t4] += __shfl_xor(SA[t4], 16, 64);
        SA[t4] += __shfl_xor(SA[t4], 32, 64);
        SB[t4] += __shfl_xor(SB[t4], 16, 64);
        SB[t4] += __shfl_xor(SB[t4], 32, 64);
    }
    if (quad == 0) {
        #pragma unroll
        for (int t4 = 0; t4 < 4; t4++) {
            Sp[(jq * BB + iA) * HH + hh * 64 + t4 * 16 + lm] = SA[t4];
            Sp[(jq * BB + iB) * HH + hh * 64 + t4 * 16 + lm] = SB[t4];
        }
    }
}

// ---------------------------------------------------------------------------
// Finish v3 (2 waves/SIMD): per row i:
//   m = (b2 + (mean_j S) @ W2)/tau ; h = relu(m@Wa+ba);
//   y = h + x@Wr + br; out = LayerNorm(y)*gamma+beta.
// Grid 1024 x 128. Block = 1 i row, lane = 1 h column.
// ---------------------------------------------------------------------------
__global__ __launch_bounds__(128) void finish_kernel(
    const float* __restrict__ Sp, const float* __restrict__ W2,
    const float* __restrict__ b2, const float* __restrict__ x,
    const float* __restrict__ Wt, const float* __restrict__ bt,
    const float* __restrict__ Wa, const float* __restrict__ ba,
    const float* __restrict__ Wr, const float* __restrict__ br,
    const float* __restrict__ gamma, const float* __restrict__ beta,
    float* __restrict__ out)
{
    __shared__ float Srow[HH];
    __shared__ float mrow[HH];
    __shared__ float xrow[DD];
    __shared__ float red[2][2];
    __shared__ float tau_s;
    const int t = threadIdx.x;      // 0..127 = h column
    const int h = t;
    const int wv = t >> 6;          // 0..1
    const int l = t & 63;
    const int i = blockIdx.x;

    {
        float s = 0.f;
        #pragma unroll
        for (int q = 0; q < 4; q++)
            s += Sp[(q * BB + i) * HH + h];
        Srow[h] = s * (1.0f / (float)BB);
    }
    if (wv == 0) {
        float xv = x[i * DD + l];
        xrow[l] = xv;
        float p = xv * Wt[l];
        #pragma unroll
        for (int off = 32; off; off >>= 1) p += __shfl_xor(p, off, 64);
        if (l == 0) {
            float z = p + bt[0];
            float sp = (z > 20.f) ? z : log1pf(expf(z));
            tau_s = fmaxf(sp, 0.01f) + 1.0f;
        }
    }
    __syncthreads();

    float acc = b2[h];
    #pragma unroll 8
    for (int k = 0; k < HH; k++)
        acc = fmaf(Srow[k], W2[k * HH + h], acc);
    const float itau = 1.0f / tau_s;
    mrow[h] = acc * itau;
    __syncthreads();

    float a2 = ba[h];
    #pragma unroll 8
    for (int k = 0; k < HH; k++)
        a2 = fmaf(mrow[k], Wa[k * HH + h], a2);
    float y = fmaxf(a2, 0.f) + br[h];
    #pragma unroll 8
    for (int d = 0; d < DD; d++)
        y = fmaf(xrow[d], Wr[d * HH + h], y);

    // LayerNorm over 128 h (2 waves): shfl tree + LDS combine
    float p = y;
    #pragma unroll
    for (int off = 32; off; off >>= 1) p += __shfl_xor(p, off, 64);
    if (l == 0) red[0][wv] = p;
    __syncthreads();
    float mu = (red[0][0] + red[0][1]) * (1.0f / (float)HH);
    float dy = y - mu;
    float q = dy * dy;
    #pragma unroll
    for (int off = 32; off; off >>= 1) q += __shfl_xor(q, off, 64);
    if (l == 0) red[1][wv] = q;
    __syncthreads();
    float rs = rsqrtf((red[1][0] + red[1][1]) * (1.0f / (float)HH) + 1e-5f);
    out[i * HH + h] = dy * rs * gamma[h] + beta[h];
}

// ---------------------------------------------------------------------------
extern "C" void kernel_launch(void* const* d_in, const int* in_sizes, int n_in,
                              void* d_out, int out_size, void* d_ws, size_t ws_size,
                              hipStream_t stream)
{
    const float* x     = (const float*)d_in[0];
    const float* W1    = (const float*)d_in[1];
    const float* b1    = (const float*)d_in[2];
    const float* W2    = (const float*)d_in[3];
    const float* b2    = (const float*)d_in[4];
    const float* Wt    = (const float*)d_in[5];
    const float* bt    = (const float*)d_in[6];
    const float* Wa    = (const float*)d_in[7];
    const float* ba    = (const float*)d_in[8];
    const float* Wr    = (const float*)d_in[9];
    const float* br    = (const float*)d_in[10];
    const float* gamma = (const float*)d_in[11];
    const float* beta  = (const float*)d_in[12];
    float* out = (float*)d_out;

    char* ws = (char*)d_ws;
    float*     c1    = (float*)(ws);                         // 512 KB
    float*     c2P   = (float*)(ws + (512 << 10));           // 512 KB
    _Float16*  wpack = (_Float16*)(ws + (1024 << 10));       // 16 KB
    float*     Sp    = (float*)(ws + (1056 << 10));          // 2 MB

    prep_kernel<<<dim3(512, 2), 256, 0, stream>>>(x, W1, b1, c1, c2P, wpack);
    pair_kernel<<<1024, 256, 0, stream>>>(x, c1, c2P, wpack, Sp);
    finish_kernel<<<1024, 128, 0, stream>>>(Sp, W2, b2, x, Wt, bt,
                                            Wa, ba, Wr, br, gamma, beta, out);
}